// Round 1
// baseline (3969.292 us; speedup 1.0000x reference)
//
#include <hip/hip_runtime.h>
#include <math.h>

#define S_LEN 2048
#define DH    64
#define NBH   32     // B*H = 2*16
#define NIDX  257    // 2*max_rel + 1

// ---------------------------------------------------------------------------
// K1: fixed sin-cos table, 257 x 64 fp32
// ---------------------------------------------------------------------------
__global__ void k_table(float* __restrict__ tab) {
    int p = blockIdx.x;          // 0..256
    int d = threadIdx.x;         // 0..63
    // div = exp(even_index * (-ln(10000)/64)), matches np float32 path
    float div = expf((float)(d & ~1) * (-0.14391156831212787f));
    float ang = (float)p * div;
    tab[p * DH + d] = (d & 1) ? cosf(ang) : sinf(ang);
}

// ---------------------------------------------------------------------------
// K2: qdA[bh][q][i] = dot(Q[bh,q,:], table[i,:])  for i in [0,257)
// block = 256 (4 waves), one wave per q-row
// ---------------------------------------------------------------------------
__global__ __launch_bounds__(256) void k_qdot(const float* __restrict__ Q,
                                              const float* __restrict__ tab,
                                              float* __restrict__ qdA) {
    int wave = threadIdx.x >> 6, lane = threadIdx.x & 63;
    int q  = blockIdx.x * 4 + wave;
    int bh = blockIdx.y;
    size_t row = (size_t)bh * S_LEN + q;
    __shared__ __align__(16) float sQ[4][DH];
    sQ[wave][lane] = Q[row * DH + lane];
    __syncthreads();
    const float4* q4 = (const float4*)sQ[wave];
    for (int i = lane; i < NIDX; i += 64) {
        const float4* t4 = (const float4*)(tab + (size_t)i * DH);
        float s = 0.f;
#pragma unroll
        for (int j = 0; j < 16; ++j) {
            float4 a = q4[j], b = t4[j];
            s += a.x * b.x + a.y * b.y + a.z * b.z + a.w * b.w;
        }
        qdA[row * NIDX + i] = s;
    }
}

// ---------------------------------------------------------------------------
// K3: flash pass. lane = q-row (64 rows/block), 4 waves split columns.
// Computes l = sum_k exp(s), out = (sum_k exp(s) * V[k]) / l, stores 1/l.
// K/V row loads are wave-uniform -> single-line broadcast loads, no LDS tile.
// ---------------------------------------------------------------------------
__global__ __launch_bounds__(256) void k_flash(const float* __restrict__ Q,
                                               const float* __restrict__ K,
                                               const float* __restrict__ V,
                                               const float* __restrict__ qdA,
                                               const int* __restrict__ pdir,
                                               float* __restrict__ out,
                                               float* __restrict__ invL) {
    __shared__ __align__(16) float ob[64][68];
    __shared__ float lb[4][64];
    int t = threadIdx.x;
    int w = t >> 6, lane = t & 63;
    int qb = 31 - (int)blockIdx.x;          // heavy blocks first (LPT)
    int bh = blockIdx.y;
    int q0 = qb * 64;
    int r  = q0 + lane;
    int causal = (*pdir) != 0;
    size_t qrow = (size_t)bh * S_LEN + r;

    const float4* q4p = (const float4*)(Q + qrow * DH);
    float4 q4[16];
#pragma unroll
    for (int j = 0; j < 16; ++j) q4[j] = q4p[j];

    const float* qdrow = qdA + qrow * NIDX;
    float qd0 = qdrow[0];
    const float4* Kb = (const float4*)(K + ((size_t)bh * S_LEN) * DH);
    const float4* Vb = (const float4*)(V + ((size_t)bh * S_LEN) * DH);

    float4 a4[16];
#pragma unroll
    for (int j = 0; j < 16; ++j) a4[j] = make_float4(0.f, 0.f, 0.f, 0.f);
    float l = 0.f;

    int kmax = causal ? (q0 + 63) : (S_LEN - 1);
    for (int k = w; k <= kmax; k += 4) {
        const float4* kr = Kb + (size_t)k * 16;
        float s = 0.f;
#pragma unroll
        for (int j = 0; j < 16; ++j) {
            float4 kv = kr[j];
            s += q4[j].x * kv.x + q4[j].y * kv.y + q4[j].z * kv.z + q4[j].w * kv.w;
        }
        int dist = k - r;
        float bias = qd0;
        if (dist >= -127) bias = qdrow[(dist > 128 ? 128 : dist) + 128];
        s = (s + bias) * 0.125f;
        float p = (!causal || dist <= 0) ? __expf(s) : 0.f;
        l += p;
        const float4* vr = Vb + (size_t)k * 16;
#pragma unroll
        for (int j = 0; j < 16; ++j) {
            float4 vv = vr[j];
            a4[j].x += p * vv.x; a4[j].y += p * vv.y;
            a4[j].z += p * vv.z; a4[j].w += p * vv.w;
        }
    }

    lb[w][lane] = l;
    // combine the 4 column-split partial accumulators in LDS
    for (int ph = 0; ph < 4; ++ph) {
        __syncthreads();
        if (w == ph) {
            if (ph == 0) {
#pragma unroll
                for (int j = 0; j < 16; ++j)
                    *(float4*)&ob[lane][j * 4] = a4[j];
            } else {
#pragma unroll
                for (int j = 0; j < 16; ++j) {
                    float4 o = *(const float4*)&ob[lane][j * 4];
                    o.x += a4[j].x; o.y += a4[j].y; o.z += a4[j].z; o.w += a4[j].w;
                    *(float4*)&ob[lane][j * 4] = o;
                }
            }
        }
    }
    __syncthreads();

    if (t < 64) {
        float lt = lb[0][t] + lb[1][t] + lb[2][t] + lb[3][t];
        invL[(size_t)bh * S_LEN + q0 + t] = 1.0f / lt;
    }

    // cooperative coalesced store of the 64x64 output tile
#pragma unroll
    for (int e = 0; e < 4; ++e) {
        int idx = t + e * 256;            // 0..1023 float4s
        int rr = idx >> 4, c4 = idx & 15;
        float lt = lb[0][rr] + lb[1][rr] + lb[2][rr] + lb[3][rr];
        float inv = 1.0f / lt;
        float4 v = *(const float4*)&ob[rr][c4 * 4];
        v.x *= inv; v.y *= inv; v.z *= inv; v.w *= inv;
        *(float4*)&out[((size_t)bh * S_LEN + q0 + rr) * DH + c4 * 4] = v;
    }
}

// ---------------------------------------------------------------------------
// K4: recompute scores, write normalized p_attn (including zero upper triangle)
// lane = q-row, 4 waves split columns within a 64-col tile; tile staged in LDS
// so global stores are coalesced.
// ---------------------------------------------------------------------------
__global__ __launch_bounds__(256) void k_pwrite(const float* __restrict__ Q,
                                                const float* __restrict__ K,
                                                const float* __restrict__ qdA,
                                                const float* __restrict__ invL,
                                                const int* __restrict__ pdir,
                                                float* __restrict__ P) {
    __shared__ __align__(16) float pt[64 * 68];
    int t = threadIdx.x;
    int w = t >> 6, lane = t & 63;
    int qb = 31 - (int)blockIdx.x;          // heavy blocks first
    int bh = blockIdx.y;
    int q0 = qb * 64;
    int r  = q0 + lane;
    int causal = (*pdir) != 0;
    size_t qrow = (size_t)bh * S_LEN + r;

    const float4* q4p = (const float4*)(Q + qrow * DH);
    float4 q4[16];
#pragma unroll
    for (int j = 0; j < 16; ++j) q4[j] = q4p[j];
    const float* qdrow = qdA + qrow * NIDX;
    float qd0 = qdrow[0];
    float inv = invL[qrow];
    const float4* Kb = (const float4*)(K + ((size_t)bh * S_LEN) * DH);
    float* Pb = P + ((size_t)bh * S_LEN) * S_LEN;

    for (int kt = 0; kt < S_LEN; kt += 64) {
        bool compute = (!causal) || (kt <= q0 + 63);
        if (compute) {
            for (int kk = w; kk < 64; kk += 4) {
                int k = kt + kk;
                const float4* kr = Kb + (size_t)k * 16;
                float s = 0.f;
#pragma unroll
                for (int j = 0; j < 16; ++j) {
                    float4 kv = kr[j];
                    s += q4[j].x * kv.x + q4[j].y * kv.y + q4[j].z * kv.z + q4[j].w * kv.w;
                }
                int dist = k - r;
                float bias = qd0;
                if (dist >= -127) bias = qdrow[(dist > 128 ? 128 : dist) + 128];
                s = (s + bias) * 0.125f;
                float p = (!causal || dist <= 0) ? __expf(s) * inv : 0.f;
                pt[lane * 68 + kk] = p;
            }
        }
        __syncthreads();
#pragma unroll
        for (int e = 0; e < 4; ++e) {
            int idx = t + e * 256;          // 0..1023 float4s of the 64x64 tile
            int rr = idx >> 4, c4 = idx & 15;
            float4 val = compute ? *(const float4*)&pt[rr * 68 + c4 * 4]
                                 : make_float4(0.f, 0.f, 0.f, 0.f);
            *(float4*)&Pb[(size_t)(q0 + rr) * S_LEN + kt + c4 * 4] = val;
        }
        __syncthreads();
    }
}

// ---------------------------------------------------------------------------
// K5: add the P·R_v band term to out.
// causal: rel = w0*table[0] + sum_{j} band[j]*table[idx0+j], w0 = 1 - sum(band)
// ---------------------------------------------------------------------------
__global__ __launch_bounds__(256) void k_relv(const float* __restrict__ P,
                                              const float* __restrict__ tab,
                                              const int* __restrict__ pdir,
                                              float* __restrict__ out) {
    int wave = threadIdx.x >> 6, lane = threadIdx.x & 63;   // lane = d
    int q  = blockIdx.x * 4 + wave;
    int bh = blockIdx.y;
    int causal = (*pdir) != 0;
    const float* Prow = P + ((size_t)bh * S_LEN + q) * S_LEN;
    float acc = 0.f;
    if (causal) {
        int k0 = q - 127; if (k0 < 0) k0 = 0;
        int n = q - k0 + 1;                 // <= 128, idx range [1,128]
        float p1 = (lane < n) ? Prow[k0 + lane] : 0.f;
        float p2 = (lane + 64 < n) ? Prow[k0 + lane + 64] : 0.f;
        float ts = p1 + p2;
#pragma unroll
        for (int m = 32; m >= 1; m >>= 1) ts += __shfl_xor(ts, m, 64);
        float w0 = 1.0f - ts;               // mass of the idx==0 bucket
        int idx0 = k0 - q + 128;
        acc = w0 * tab[lane];               // table[0][d]
        int n1 = n < 64 ? n : 64;
        for (int j = 0; j < n1; ++j) {
            float pj = __shfl(p1, j, 64);
            acc += pj * tab[(size_t)(idx0 + j) * DH + lane];
        }
        for (int j = 64; j < n; ++j) {
            float pj = __shfl(p2, j - 64, 64);
            acc += pj * tab[(size_t)(idx0 + j) * DH + lane];
        }
    } else {
        for (int kc = 0; kc < S_LEN; kc += 64) {
            float pv = Prow[kc + lane];
            for (int j = 0; j < 64; ++j) {
                float pj = __shfl(pv, j, 64);
                int dist = kc + j - q;
                int idx = dist < -128 ? 0 : (dist > 128 ? 256 : dist + 128);
                acc += pj * tab[(size_t)idx * DH + lane];
            }
        }
    }
    out[((size_t)bh * S_LEN + q) * DH + lane] += acc;
}

// ---------------------------------------------------------------------------
extern "C" void kernel_launch(void* const* d_in, const int* in_sizes, int n_in,
                              void* d_out, int out_size, void* d_ws, size_t ws_size,
                              hipStream_t stream) {
    const float* Q = (const float*)d_in[0];
    const float* K = (const float*)d_in[1];
    const float* V = (const float*)d_in[2];
    const int* dir = (const int*)d_in[3];

    float* out = (float*)d_out;                            // [32,2048,64]
    float* P   = out + (size_t)NBH * S_LEN * DH;           // [32,2048,2048]

    char* ws = (char*)d_ws;
    float* tab  = (float*)ws;                              // 257*64*4   = 65,792 B
    float* invL = (float*)(ws + 65792);                    // 65536*4    = 262,144 B
    float* qdA  = (float*)(ws + 65792 + 262144);           // 32*2048*257*4 = 67.4 MB

    hipLaunchKernelGGL(k_table, dim3(NIDX), dim3(DH), 0, stream, tab);
    hipLaunchKernelGGL(k_qdot, dim3(S_LEN / 4, NBH), dim3(256), 0, stream, Q, tab, qdA);
    hipLaunchKernelGGL(k_flash, dim3(32, NBH), dim3(256), 0, stream,
                       Q, K, V, qdA, dir, out, invL);
    hipLaunchKernelGGL(k_pwrite, dim3(32, NBH), dim3(256), 0, stream,
                       Q, K, qdA, invL, dir, P);
    hipLaunchKernelGGL(k_relv, dim3(S_LEN / 4, NBH), dim3(256), 0, stream,
                       P, tab, dir, out);
}

// Round 2
// 1644.998 us; speedup vs baseline: 2.4129x; 2.4129x over previous
//
#include <hip/hip_runtime.h>
#include <math.h>

#define S_LEN 2048
#define DH    64
#define NBH   32     // B*H
#define NIDX  257    // 2*max_rel + 1

typedef _Float16 f16;
typedef f16 f16x8 __attribute__((ext_vector_type(8)));
typedef float f32x4 __attribute__((ext_vector_type(4)));

// ---------------------------------------------------------------------------
// K1: fixed sin-cos table, 257 x 64 fp32
// ---------------------------------------------------------------------------
__global__ void k_table(float* __restrict__ tab) {
    int p = blockIdx.x, d = threadIdx.x;
    float div = expf((float)(d & ~1) * (-0.14391156831212787f));
    float ang = (float)p * div;
    tab[p * DH + d] = (d & 1) ? cosf(ang) : sinf(ang);
}

// ---------------------------------------------------------------------------
// K2: elementwise cast K -> f16 (row-major kept)
// ---------------------------------------------------------------------------
__global__ __launch_bounds__(256) void k_cast(const float* __restrict__ src,
                                              f16* __restrict__ dst, int n8) {
    int i = blockIdx.x * blockDim.x + threadIdx.x;
    int stride = gridDim.x * blockDim.x;
    for (; i < n8; i += stride) {
        const float4* p = (const float4*)(src + (size_t)i * 8);
        float4 a = p[0], b = p[1];
        f16x8 v;
        v[0]=(f16)a.x; v[1]=(f16)a.y; v[2]=(f16)a.z; v[3]=(f16)a.w;
        v[4]=(f16)b.x; v[5]=(f16)b.y; v[6]=(f16)b.z; v[7]=(f16)b.w;
        *(f16x8*)(dst + (size_t)i * 8) = v;
    }
}

// ---------------------------------------------------------------------------
// K3: V transpose+cast: VhT[bh][d][k] f16
// ---------------------------------------------------------------------------
__global__ __launch_bounds__(256) void k_vt(const float* __restrict__ V,
                                            f16* __restrict__ VhT) {
    __shared__ float sT[64][65];
    int t = threadIdx.x;
    int k0 = blockIdx.x * 64, bh = blockIdx.y;
#pragma unroll
    for (int i = 0; i < 4; ++i) {
        int c = t + i * 256;            // 0..1023 float4s of the 64x64 tile
        int k = c >> 4, d4 = c & 15;
        float4 v = *(const float4*)(V + ((size_t)bh * S_LEN + k0 + k) * DH + d4 * 4);
        sT[k][d4 * 4 + 0] = v.x; sT[k][d4 * 4 + 1] = v.y;
        sT[k][d4 * 4 + 2] = v.z; sT[k][d4 * 4 + 3] = v.w;
    }
    __syncthreads();
    int d = t >> 2, kq = t & 3;
    f16 buf[16];
#pragma unroll
    for (int i = 0; i < 16; ++i) buf[i] = (f16)sT[kq * 16 + i][d];
    f16* dst = VhT + ((size_t)bh * DH + d) * S_LEN + k0 + kq * 16;
    *(f16x8*)dst = *(f16x8*)&buf[0];
    *(f16x8*)(dst + 8) = *(f16x8*)&buf[8];
}

// ---------------------------------------------------------------------------
// K4: qdAh[bh][q][i] = (f16) dot(Q[bh,q,:], table[i,:])
// ---------------------------------------------------------------------------
__global__ __launch_bounds__(256) void k_qdot(const float* __restrict__ Q,
                                              const float* __restrict__ tab,
                                              f16* __restrict__ qdAh) {
    int wave = threadIdx.x >> 6, lane = threadIdx.x & 63;
    int q  = blockIdx.x * 4 + wave;
    int bh = blockIdx.y;
    size_t row = (size_t)bh * S_LEN + q;
    __shared__ __align__(16) float sQ[4][DH];
    sQ[wave][lane] = Q[row * DH + lane];
    __syncthreads();
    const float4* q4 = (const float4*)sQ[wave];
    for (int i = lane; i < NIDX; i += 64) {
        const float4* t4 = (const float4*)(tab + (size_t)i * DH);
        float s = 0.f;
#pragma unroll
        for (int j = 0; j < 16; ++j) {
            float4 a = q4[j], b = t4[j];
            s += a.x * b.x + a.y * b.y + a.z * b.z + a.w * b.w;
        }
        qdAh[row * NIDX + i] = (f16)s;
    }
}

// ---------------------------------------------------------------------------
// K5: MFMA flash. Block p handles q-tiles {p, 31-p} (uniform work pairing).
// Wave w owns q-rows [q0+w*16, +16). No __syncthreads in the k-loop: B-frags
// come straight from global f16 (L1/L2-warm); P round-trips through a
// per-wave-private LDS strip for the C->A relayout.
// ---------------------------------------------------------------------------
__global__ __launch_bounds__(256) void k_flash(const float* __restrict__ Q,
                                               const f16* __restrict__ Kh,
                                               const f16* __restrict__ VhT,
                                               const f16* __restrict__ qdAh,
                                               const int* __restrict__ pdir,
                                               float* __restrict__ out,
                                               float* __restrict__ invL) {
    __shared__ f16 pt[64][72];
    int t = threadIdx.x, w = t >> 6, lane = t & 63;
    int quad = lane >> 4, l15 = lane & 15;
    int bh = blockIdx.y;
    int causal = (*pdir) != 0;
    const f16* KhB = Kh + (size_t)bh * S_LEN * DH;
    const f16* VtB = VhT + (size_t)bh * DH * S_LEN;

    for (int qsel = 0; qsel < 2; ++qsel) {
        int qb = qsel ? (31 - (int)blockIdx.x) : (int)blockIdx.x;
        int q0 = qb * 64;
        int rbase = q0 + w * 16;

        f16x8 qa[2];
        {
            const float* qrow = Q + ((size_t)bh * S_LEN + rbase + l15) * DH;
#pragma unroll
            for (int s = 0; s < 2; ++s) {
                const float4* p4 = (const float4*)(qrow + s * 32 + quad * 8);
                float4 x = p4[0], y = p4[1];
                f16x8 v;
                v[0]=(f16)x.x; v[1]=(f16)x.y; v[2]=(f16)x.z; v[3]=(f16)x.w;
                v[4]=(f16)y.x; v[5]=(f16)y.y; v[6]=(f16)y.z; v[7]=(f16)y.w;
                qa[s] = v;
            }
        }
        int rows[4];
        const f16* qdrow[4];
#pragma unroll
        for (int reg = 0; reg < 4; ++reg) {
            rows[reg] = rbase + quad * 4 + reg;
            qdrow[reg] = qdAh + ((size_t)bh * S_LEN + rows[reg]) * NIDX;
        }
        f32x4 oacc[4];
#pragma unroll
        for (int n = 0; n < 4; ++n) oacc[n] = (f32x4){0.f, 0.f, 0.f, 0.f};
        float rsum[4] = {0.f, 0.f, 0.f, 0.f};

        int kend = causal ? qb : 31;
        for (int kt = 0; kt <= kend; ++kt) {
            int kc0 = kt * 64;
            f32x4 sfr[4];
#pragma unroll
            for (int n = 0; n < 4; ++n) {
                f32x4 acc = (f32x4){0.f, 0.f, 0.f, 0.f};
#pragma unroll
                for (int s = 0; s < 2; ++s) {
                    f16x8 kb = *(const f16x8*)(KhB + (size_t)(kc0 + n * 16 + l15) * DH + s * 32 + quad * 8);
                    acc = __builtin_amdgcn_mfma_f32_16x16x32_f16(qa[s], kb, acc, 0, 0, 0);
                }
                sfr[n] = acc;
            }
#pragma unroll
            for (int n = 0; n < 4; ++n) {
                int col = kc0 + n * 16 + l15;
#pragma unroll
                for (int reg = 0; reg < 4; ++reg) {
                    int dist = col - rows[reg];
                    float p;
                    if (causal && dist > 0) {
                        p = 0.f;
                    } else {
                        int idx = dist < -128 ? 0 : (dist > 128 ? 256 : dist + 128);
                        float b = (float)qdrow[reg][idx];
                        p = __expf((sfr[n][reg] + b) * 0.125f);
                    }
                    rsum[reg] += p;
                    pt[w * 16 + quad * 4 + reg][n * 16 + l15] = (f16)p;
                }
            }
#pragma unroll
            for (int s = 0; s < 2; ++s) {
                f16x8 pa = *(const f16x8*)&pt[w * 16 + l15][s * 32 + quad * 8];
#pragma unroll
                for (int n = 0; n < 4; ++n) {
                    f16x8 vb = *(const f16x8*)(VtB + (size_t)(n * 16 + l15) * S_LEN + kc0 + s * 32 + quad * 8);
                    oacc[n] = __builtin_amdgcn_mfma_f32_16x16x32_f16(pa, vb, oacc[n], 0, 0, 0);
                }
            }
        }

        float inv[4];
#pragma unroll
        for (int reg = 0; reg < 4; ++reg) {
            float v = rsum[reg];
            v += __shfl_xor(v, 1, 64);
            v += __shfl_xor(v, 2, 64);
            v += __shfl_xor(v, 4, 64);
            v += __shfl_xor(v, 8, 64);
            inv[reg] = 1.0f / v;
            if (l15 == 0) invL[(size_t)bh * S_LEN + rows[reg]] = inv[reg];
        }
#pragma unroll
        for (int n = 0; n < 4; ++n)
#pragma unroll
            for (int reg = 0; reg < 4; ++reg)
                out[((size_t)bh * S_LEN + rows[reg]) * DH + n * 16 + l15] = oacc[n][reg] * inv[reg];
    }
}

// ---------------------------------------------------------------------------
// K6: recompute scores via MFMA, write normalized p_attn + zero upper tiles.
// ---------------------------------------------------------------------------
__global__ __launch_bounds__(256) void k_pwrite(const float* __restrict__ Q,
                                                const f16* __restrict__ Kh,
                                                const f16* __restrict__ qdAh,
                                                const float* __restrict__ invL,
                                                const int* __restrict__ pdir,
                                                float* __restrict__ P) {
    int t = threadIdx.x, w = t >> 6, lane = t & 63;
    int quad = lane >> 4, l15 = lane & 15;
    int bh = blockIdx.y;
    int causal = (*pdir) != 0;
    const f16* KhB = Kh + (size_t)bh * S_LEN * DH;
    float* Pq = P + (size_t)bh * S_LEN * S_LEN;

    for (int qsel = 0; qsel < 2; ++qsel) {
        int qb = qsel ? (31 - (int)blockIdx.x) : (int)blockIdx.x;
        int q0 = qb * 64;
        int rbase = q0 + w * 16;

        f16x8 qa[2];
        {
            const float* qrow = Q + ((size_t)bh * S_LEN + rbase + l15) * DH;
#pragma unroll
            for (int s = 0; s < 2; ++s) {
                const float4* p4 = (const float4*)(qrow + s * 32 + quad * 8);
                float4 x = p4[0], y = p4[1];
                f16x8 v;
                v[0]=(f16)x.x; v[1]=(f16)x.y; v[2]=(f16)x.z; v[3]=(f16)x.w;
                v[4]=(f16)y.x; v[5]=(f16)y.y; v[6]=(f16)y.z; v[7]=(f16)y.w;
                qa[s] = v;
            }
        }
        int rows[4];
        const f16* qdrow[4];
        float inv[4];
#pragma unroll
        for (int reg = 0; reg < 4; ++reg) {
            rows[reg] = rbase + quad * 4 + reg;
            qdrow[reg] = qdAh + ((size_t)bh * S_LEN + rows[reg]) * NIDX;
            inv[reg] = invL[(size_t)bh * S_LEN + rows[reg]];
        }

        for (int kt = 0; kt < 32; ++kt) {
            int kc0 = kt * 64;
            if (!causal || kt <= qb) {
                f32x4 sfr[4];
#pragma unroll
                for (int n = 0; n < 4; ++n) {
                    f32x4 acc = (f32x4){0.f, 0.f, 0.f, 0.f};
#pragma unroll
                    for (int s = 0; s < 2; ++s) {
                        f16x8 kb = *(const f16x8*)(KhB + (size_t)(kc0 + n * 16 + l15) * DH + s * 32 + quad * 8);
                        acc = __builtin_amdgcn_mfma_f32_16x16x32_f16(qa[s], kb, acc, 0, 0, 0);
                    }
                    sfr[n] = acc;
                }
#pragma unroll
                for (int n = 0; n < 4; ++n) {
                    int col = kc0 + n * 16 + l15;
#pragma unroll
                    for (int reg = 0; reg < 4; ++reg) {
                        int dist = col - rows[reg];
                        float p;
                        if (causal && dist > 0) {
                            p = 0.f;
                        } else {
                            int idx = dist < -128 ? 0 : (dist > 128 ? 256 : dist + 128);
                            float b = (float)qdrow[reg][idx];
                            p = __expf((sfr[n][reg] + b) * 0.125f) * inv[reg];
                        }
                        Pq[(size_t)rows[reg] * S_LEN + col] = p;
                    }
                }
            } else {
                float4 z = make_float4(0.f, 0.f, 0.f, 0.f);
#pragma unroll
                for (int e = 0; e < 4; ++e) {
                    int idx = t + e * 256;
                    int rr = idx >> 4, c4 = idx & 15;
                    *(float4*)&Pq[(size_t)(q0 + rr) * S_LEN + kc0 + c4 * 4] = z;
                }
            }
        }
    }
}

// ---------------------------------------------------------------------------
// K7: add the P·R_v band term to out (unchanged from round 1; verified).
// ---------------------------------------------------------------------------
__global__ __launch_bounds__(256) void k_relv(const float* __restrict__ P,
                                              const float* __restrict__ tab,
                                              const int* __restrict__ pdir,
                                              float* __restrict__ out) {
    int wave = threadIdx.x >> 6, lane = threadIdx.x & 63;   // lane = d
    int q  = blockIdx.x * 4 + wave;
    int bh = blockIdx.y;
    int causal = (*pdir) != 0;
    const float* Prow = P + ((size_t)bh * S_LEN + q) * S_LEN;
    float acc = 0.f;
    if (causal) {
        int k0 = q - 127; if (k0 < 0) k0 = 0;
        int n = q - k0 + 1;
        float p1 = (lane < n) ? Prow[k0 + lane] : 0.f;
        float p2 = (lane + 64 < n) ? Prow[k0 + lane + 64] : 0.f;
        float ts = p1 + p2;
#pragma unroll
        for (int m = 32; m >= 1; m >>= 1) ts += __shfl_xor(ts, m, 64);
        float w0 = 1.0f - ts;
        int idx0 = k0 - q + 128;
        acc = w0 * tab[lane];
        int n1 = n < 64 ? n : 64;
        for (int j = 0; j < n1; ++j) {
            float pj = __shfl(p1, j, 64);
            acc += pj * tab[(size_t)(idx0 + j) * DH + lane];
        }
        for (int j = 64; j < n; ++j) {
            float pj = __shfl(p2, j - 64, 64);
            acc += pj * tab[(size_t)(idx0 + j) * DH + lane];
        }
    } else {
        for (int kc = 0; kc < S_LEN; kc += 64) {
            float pv = Prow[kc + lane];
            for (int j = 0; j < 64; ++j) {
                float pj = __shfl(pv, j, 64);
                int dist = kc + j - q;
                int idx = dist < -128 ? 0 : (dist > 128 ? 256 : dist + 128);
                acc += pj * tab[(size_t)idx * DH + lane];
            }
        }
    }
    out[((size_t)bh * S_LEN + q) * DH + lane] += acc;
}

// ---------------------------------------------------------------------------
extern "C" void kernel_launch(void* const* d_in, const int* in_sizes, int n_in,
                              void* d_out, int out_size, void* d_ws, size_t ws_size,
                              hipStream_t stream) {
    const float* Q = (const float*)d_in[0];
    const float* K = (const float*)d_in[1];
    const float* V = (const float*)d_in[2];
    const int* dir = (const int*)d_in[3];

    float* out = (float*)d_out;                            // [32,2048,64]
    float* P   = out + (size_t)NBH * S_LEN * DH;           // [32,2048,2048]

    char* ws = (char*)d_ws;
    float* tab  = (float*)ws;                              // 65,792 B
    float* invL = (float*)(ws + 65792);                    // 262,144 B
    f16*   qdAh = (f16*)(ws + 327936);                     // 33,685,504 B
    f16*   Kh   = (f16*)(ws + 34013440);                   // 8,388,608 B
    f16*   VhT  = (f16*)(ws + 42402048);                   // 8,388,608 B

    k_table<<<dim3(NIDX), dim3(DH), 0, stream>>>(tab);
    k_cast<<<dim3(1024), dim3(256), 0, stream>>>(K, Kh, NBH * S_LEN * DH / 8);
    k_vt<<<dim3(S_LEN / 64, NBH), dim3(256), 0, stream>>>(V, VhT);
    k_qdot<<<dim3(S_LEN / 4, NBH), dim3(256), 0, stream>>>(Q, tab, qdAh);
    k_flash<<<dim3(16, NBH), dim3(256), 0, stream>>>(Q, Kh, VhT, qdAh, dir, out, invL);
    k_pwrite<<<dim3(16, NBH), dim3(256), 0, stream>>>(Q, Kh, qdAh, invL, dir, P);
    k_relv<<<dim3(S_LEN / 4, NBH), dim3(256), 0, stream>>>(P, tab, dir, out);
}